// Round 6
// baseline (1262.613 us; speedup 1.0000x reference)
//
#include <hip/hip_runtime.h>
#include <hip/hip_bf16.h>

// Problem dims (fixed)
#define Bdim 16
#define Sdim 512
#define Ddim 512
#define Hdim 8
#define DKdim 64
#define Fdim 2048
#define Mrows (Bdim * Sdim)   // 8192

typedef __attribute__((ext_vector_type(8))) short  frag16;   // 8 bf16 (4 VGPRs)
typedef __attribute__((ext_vector_type(4))) float  f32x4;    // MFMA acc
typedef __attribute__((ext_vector_type(8))) unsigned short ushort8;
typedef __attribute__((ext_vector_type(4))) unsigned short ushort4v;
typedef __attribute__((ext_vector_type(2))) __fp16 half2v;

// round-to-nearest-even fp32 -> bf16 (finite data)
__device__ __forceinline__ unsigned short f2b(float x) {
    union { float f; unsigned int u; } v; v.f = x;
    unsigned int r = (v.u + 0x7FFFu + ((v.u >> 16) & 1u)) >> 16;
    return (unsigned short)r;
}

union H2U { unsigned int u; half2v h; };
__device__ __forceinline__ unsigned int pk2(float a, float b) {
    H2U x; x.h = __builtin_amdgcn_cvt_pkrtz(a, b); return x.u;
}
__device__ __forceinline__ float upk(unsigned int u, int i) {
    H2U x; x.u = u; return (float)x.h[i];
}

// ---------------------------------------------------------------------------
// bf16 MFMA GEMM, 128x128 tile (used for FFN1, N=2048)
// ---------------------------------------------------------------------------
__global__ __launch_bounds__(256) void gemm_mfma(
    const __hip_bfloat16* __restrict__ A, const __hip_bfloat16* __restrict__ Bt,
    const float* __restrict__ bias, const float* __restrict__ R,
    float* __restrict__ Cf, unsigned short* __restrict__ Cb,
    int M, int N, int K, int do_relu)
{
    __shared__ short As[128 * 32];
    __shared__ short Bs[128 * 32];

    const int t = threadIdx.x;
    const int lane = t & 63;
    const int wave = t >> 6;
    const int bm = blockIdx.y * 128;
    const int bn = blockIdx.x * 128;
    const int wm = (wave >> 1) * 64;
    const int wn = (wave & 1) * 64;

    f32x4 acc[4][4] = {};
    const int lrow = lane >> 2;
    const int lcol = (lane & 3) * 8;

    for (int k0 = 0; k0 < K; k0 += 32) {
#pragma unroll
        for (int i = 0; i < 2; ++i) {
            const int chunk = wave * 2 + i;
            const int row = chunk * 16 + lrow;
            const __hip_bfloat16* ga = A + (size_t)(bm + row) * K + k0 + lcol;
            const __hip_bfloat16* gb = Bt + (size_t)(bn + row) * K + k0 + lcol;
            __builtin_amdgcn_global_load_lds(
                (const __attribute__((address_space(1))) unsigned int*)ga,
                (__attribute__((address_space(3))) unsigned int*)(As + chunk * 512),
                16, 0, 0);
            __builtin_amdgcn_global_load_lds(
                (const __attribute__((address_space(1))) unsigned int*)gb,
                (__attribute__((address_space(3))) unsigned int*)(Bs + chunk * 512),
                16, 0, 0);
        }
        __syncthreads();

        const int fr = lane & 15;
        const int quad = lane >> 4;
        frag16 af[4], bfr[4];
#pragma unroll
        for (int i = 0; i < 4; ++i) {
            af[i]  = *(const frag16*)(As + (wm + i * 16 + fr) * 32 + quad * 8);
            bfr[i] = *(const frag16*)(Bs + (wn + i * 16 + fr) * 32 + quad * 8);
        }
#pragma unroll
        for (int mi = 0; mi < 4; ++mi)
#pragma unroll
            for (int ni = 0; ni < 4; ++ni)
                acc[mi][ni] = __builtin_amdgcn_mfma_f32_16x16x32_bf16(
                    af[mi], bfr[ni], acc[mi][ni], 0, 0, 0);
        __syncthreads();
    }

    const int fr = lane & 15;
    const int quad = lane >> 4;
#pragma unroll
    for (int mi = 0; mi < 4; ++mi) {
#pragma unroll
        for (int r = 0; r < 4; ++r) {
            const int m = bm + wm + mi * 16 + quad * 4 + r;
#pragma unroll
            for (int ni = 0; ni < 4; ++ni) {
                const int n = bn + wn + ni * 16 + fr;
                float v = acc[mi][ni][r] + bias[n];
                if (R) v += R[(size_t)m * N + n];
                if (do_relu) v = fmaxf(v, 0.f);
                if (Cf) Cf[(size_t)m * N + n] = v;
                if (Cb) Cb[(size_t)m * N + n] = f2b(v);
            }
        }
    }
}

// ---------------------------------------------------------------------------
// bf16 MFMA GEMM, 128x64 tile, N=512 fixed. Dual-mode via blockIdx.z:
// z=0: A0@B0^T+bias0 -> Cb (normal bf16) / Cf(+R) fp32
// z=1: A1@B1^T+bias1 -> CbT transposed Vt[b,h,d,s] bf16
// ---------------------------------------------------------------------------
__global__ __launch_bounds__(256) void gemm_n64(
    const unsigned short* __restrict__ A0, const unsigned short* __restrict__ A1,
    const unsigned short* __restrict__ B0, const unsigned short* __restrict__ B1,
    const float* __restrict__ bias0, const float* __restrict__ bias1,
    const float* __restrict__ R, float* __restrict__ Cf,
    unsigned short* __restrict__ Cb, unsigned short* __restrict__ CbT,
    int K)
{
    const int NN = 512;
    __shared__ short As[128 * 32];
    __shared__ short Bs[64 * 32];

    const int trans = blockIdx.z;
    const unsigned short* A  = trans ? A1 : A0;
    const unsigned short* Bt = trans ? B1 : B0;
    const float* bias        = trans ? bias1 : bias0;

    const int t = threadIdx.x;
    const int lane = t & 63;
    const int wave = t >> 6;
    const int bm = blockIdx.y * 128;
    const int bn = blockIdx.x * 64;
    const int wm = (wave >> 1) * 64;
    const int wn = (wave & 1) * 32;

    f32x4 acc[4][2] = {};
    const int lrow = lane >> 2;
    const int lcol = (lane & 3) * 8;

    for (int k0 = 0; k0 < K; k0 += 32) {
#pragma unroll
        for (int i = 0; i < 2; ++i) {
            const int chunk = wave * 2 + i;
            const int row = chunk * 16 + lrow;
            const unsigned short* ga = A + (size_t)(bm + row) * K + k0 + lcol;
            __builtin_amdgcn_global_load_lds(
                (const __attribute__((address_space(1))) unsigned int*)ga,
                (__attribute__((address_space(3))) unsigned int*)(As + chunk * 512),
                16, 0, 0);
        }
        {
            const int row = wave * 16 + lrow;
            const unsigned short* gb = Bt + (size_t)(bn + row) * K + k0 + lcol;
            __builtin_amdgcn_global_load_lds(
                (const __attribute__((address_space(1))) unsigned int*)gb,
                (__attribute__((address_space(3))) unsigned int*)(Bs + wave * 512),
                16, 0, 0);
        }
        __syncthreads();

        const int fr = lane & 15;
        const int quad = lane >> 4;
        frag16 af[4], bfr[2];
#pragma unroll
        for (int i = 0; i < 4; ++i)
            af[i] = *(const frag16*)(As + (wm + i * 16 + fr) * 32 + quad * 8);
#pragma unroll
        for (int i = 0; i < 2; ++i)
            bfr[i] = *(const frag16*)(Bs + (wn + i * 16 + fr) * 32 + quad * 8);
#pragma unroll
        for (int mi = 0; mi < 4; ++mi)
#pragma unroll
            for (int ni = 0; ni < 2; ++ni)
                acc[mi][ni] = __builtin_amdgcn_mfma_f32_16x16x32_bf16(
                    af[mi], bfr[ni], acc[mi][ni], 0, 0, 0);
        __syncthreads();
    }

    const int fr = lane & 15;
    const int quad = lane >> 4;

    if (trans) {
#pragma unroll
        for (int mi = 0; mi < 4; ++mi)
#pragma unroll
            for (int ni = 0; ni < 2; ++ni) {
                const int m = bm + wm + mi * 16 + quad * 4;
                const int n = bn + wn + ni * 16 + fr;
                ushort4v o;
#pragma unroll
                for (int r = 0; r < 4; ++r) o[r] = f2b(acc[mi][ni][r] + bias[n]);
                const int bb = m >> 9, s = m & 511;
                const int hh = n >> 6, dd = n & 63;
                *(ushort4v*)(CbT + (((size_t)((bb * Hdim + hh) * DKdim + dd)) << 9) + s) = o;
            }
        return;
    }

#pragma unroll
    for (int mi = 0; mi < 4; ++mi) {
#pragma unroll
        for (int r = 0; r < 4; ++r) {
            const int m = bm + wm + mi * 16 + quad * 4 + r;
#pragma unroll
            for (int ni = 0; ni < 2; ++ni) {
                const int n = bn + wn + ni * 16 + fr;
                float v = acc[mi][ni][r] + bias[n];
                if (R) v += R[(size_t)m * NN + n];
                if (Cf) Cf[(size_t)m * NN + n] = v;
                if (Cb) Cb[(size_t)m * NN + n] = f2b(v);
            }
        }
    }
}

// ---------------------------------------------------------------------------
// fp32 -> bf16 convert
// ---------------------------------------------------------------------------
__global__ __launch_bounds__(256) void conv_b(
    const float* __restrict__ X, unsigned short* __restrict__ Y)
{
    const size_t i = ((size_t)blockIdx.x * 256 + threadIdx.x) * 8;
    float4 a = *(const float4*)(X + i);
    float4 b = *(const float4*)(X + i + 4);
    ushort8 o;
    o[0] = f2b(a.x); o[1] = f2b(a.y); o[2] = f2b(a.z); o[3] = f2b(a.w);
    o[4] = f2b(b.x); o[5] = f2b(b.y); o[6] = f2b(b.z); o[7] = f2b(b.w);
    *(ushort8*)(Y + i) = o;
}

// ---------------------------------------------------------------------------
// ALL weight transposes fused: 1600 tiles of 64x64, [K,N] fp32 -> [N,K] bf16
// dst layout: 9 x Wk/Wv/Wo (l*3+which), then W1 (layers 0,2), then W2 (0,2)
// ---------------------------------------------------------------------------
__global__ __launch_bounds__(256) void wtrans_all(
    const float* __restrict__ Wk, const float* __restrict__ Wv,
    const float* __restrict__ Wo, const float* __restrict__ W1,
    const float* __restrict__ W2, unsigned short* __restrict__ dst)
{
    const int bid = blockIdx.x;
    const float* src; unsigned short* d; int K, N, tk, tn;
    if (bid < 576) {
        const int mat = bid >> 6, tile = bid & 63;
        const int l = mat / 3, wch = mat % 3;
        const float* W = (wch == 0) ? Wk : (wch == 1) ? Wv : Wo;
        src = W + (size_t)l * 262144;
        d = dst + (size_t)mat * 262144;
        K = 512; N = 512; tn = tile & 7; tk = tile >> 3;
    } else if (bid < 1088) {
        const int idx = bid - 576, l2 = idx >> 8, tile = idx & 255;
        src = W1 + (size_t)(l2 * 2) * (512 * 2048);
        d = dst + 9 * 262144 + (size_t)l2 * (512 * 2048);
        K = 512; N = 2048; tn = tile & 31; tk = tile >> 5;
    } else {
        const int idx = bid - 1088, l2 = idx >> 8, tile = idx & 255;
        src = W2 + (size_t)(l2 * 2) * (2048 * 512);
        d = dst + 9 * 262144 + 2 * (512 * 2048) + (size_t)l2 * (2048 * 512);
        K = 2048; N = 512; tn = tile & 7; tk = tile >> 3;
    }
    const int n0 = tn * 64, k0 = tk * 64;
    __shared__ float T[64][65];
    const int t = threadIdx.x;
    const int kl = t >> 4, n4 = (t & 15) << 2;
#pragma unroll
    for (int it = 0; it < 4; ++it) {
        const int k = kl + it * 16;
        float4 v = *(const float4*)(src + (size_t)(k0 + k) * N + n0 + n4);
        T[n4 + 0][k] = v.x; T[n4 + 1][k] = v.y;
        T[n4 + 2][k] = v.z; T[n4 + 3][k] = v.w;
    }
    __syncthreads();
    const int nl = t >> 3, k8 = (t & 7) << 3;
#pragma unroll
    for (int it = 0; it < 2; ++it) {
        const int n = nl + it * 32;
        ushort8 o;
#pragma unroll
        for (int c = 0; c < 8; ++c) o[c] = f2b(T[n][k8 + c]);
        *(ushort8*)(d + (size_t)(n0 + n) * K + k0 + k8) = o;
    }
}

// ---------------------------------------------------------------------------
// Monotonic attention v3. One wave = 16 q-rows; 4 independent waves/block.
// QK^T + PV on MFMA; softmax/suffix-cumsum register-resident (fp16-packed
// score/suffix arrays, shfl-based scans). Chunked LDS staging for PV.
// ---------------------------------------------------------------------------
#define PSTR 264   // LDS row stride (bf16 elems): 528 B = 33x16 B, banks +4/row

__global__ __launch_bounds__(256, 3) void attn_v3(
    const unsigned short* __restrict__ Kb,   // [B*S, D] bf16 (Q == K)
    const unsigned short* __restrict__ Vt,   // [B,H,DK,S] bf16
    const float* __restrict__ gam,
    unsigned short* __restrict__ Ob,         // [B*S, D] bf16
    int mask_type)
{
    __shared__ unsigned short Pch[4][16 * PSTR];   // 33 KB

    const int qt = blockIdx.x, h = blockIdx.y, b = blockIdx.z;
    const int t = threadIdx.x, lane = t & 63, w = t >> 6;
    const int quad = lane >> 4, fr = lane & 15;
    const int q0 = qt * 64 + w * 16;
    const float NEGC = -49152.0f;   // fp16-exact sentinel

    const unsigned short* kbase = Kb + (size_t)b * Sdim * Ddim + h * DKdim;

    frag16 aq0 = *(const frag16*)(kbase + (size_t)(q0 + fr) * Ddim + quad * 8);
    frag16 aq1 = *(const frag16*)(kbase + (size_t)(q0 + fr) * Ddim + 32 + quad * 8);

    unsigned int P01[32], P23[32], Q01[32], Q23[32];
    float m1[4] = {NEGC, NEGC, NEGC, NEGC};
    const int i0 = q0 + quad * 4;

    // ---- Phase 1: QK^T MFMA, scale+mask, running row-max, pack s (fp16)
#pragma unroll
    for (int jn = 0; jn < 32; ++jn) {
        frag16 b0 = *(const frag16*)(kbase + (size_t)(jn * 16 + fr) * Ddim + quad * 8);
        frag16 b1 = *(const frag16*)(kbase + (size_t)(jn * 16 + fr) * Ddim + 32 + quad * 8);
        f32x4 z = {0.f, 0.f, 0.f, 0.f};
        z = __builtin_amdgcn_mfma_f32_16x16x32_bf16(aq0, b0, z, 0, 0, 0);
        z = __builtin_amdgcn_mfma_f32_16x16x32_bf16(aq1, b1, z, 0, 0, 0);
        const int j = jn * 16 + fr;
        float sv[4];
#pragma unroll
        for (int r = 0; r < 4; ++r) {
            const bool valid = mask_type ? (j <= i0 + r) : (j < i0 + r);
            const float s = valid ? z[r] * 0.125f : NEGC;
            sv[r] = s;
            m1[r] = fmaxf(m1[r], s);
        }
        P01[jn] = pk2(sv[0], sv[1]);
        P23[jn] = pk2(sv[2], sv[3]);
    }
#pragma unroll
    for (int r = 0; r < 4; ++r)
#pragma unroll
        for (int o = 1; o <= 8; o <<= 1) m1[r] = fmaxf(m1[r], __shfl_xor(m1[r], o));

    // ---- Phase 2: e1 + streaming suffix-scan (strict), pack suffix (fp16)
    float U[4] = {0.f, 0.f, 0.f, 0.f};
#pragma unroll
    for (int jn = 31; jn >= 0; --jn) {
        float sv[4] = {upk(P01[jn], 0), upk(P01[jn], 1), upk(P23[jn], 0), upk(P23[jn], 1)};
        float suf[4];
#pragma unroll
        for (int r = 0; r < 4; ++r) {
            const float e = __expf(sv[r] - m1[r]);
            float incl = e;
#pragma unroll
            for (int o = 1; o <= 8; o <<= 1) {
                const float v = __shfl_down(incl, o);
                incl += (fr + o < 16) ? v : 0.f;
            }
            const float Tt = __shfl(incl, lane & 48);   // group lane 0 = tile total
            suf[r] = U[r] + (incl - e);                 // strict suffix
            U[r] += Tt;
        }
        Q01[jn] = pk2(suf[0], suf[1]);
        Q23[jn] = pk2(suf[2], suf[3]);
    }
    // U == sum1 (uniform within 16-lane group)

    // ---- Phase 3: distance decay + decayed scores, pack s2
    const float gneg = -log1pf(__expf(gam[h]));
    float rs1[4], m2[4] = {NEGC, NEGC, NEGC, NEGC};
#pragma unroll
    for (int r = 0; r < 4; ++r) rs1[r] = 1.f / U[r];
#pragma unroll
    for (int jn = 0; jn < 32; ++jn) {
        const int j = jn * 16 + fr;
        float sv[4] = {upk(P01[jn], 0), upk(P01[jn], 1), upk(P23[jn], 0), upk(P23[jn], 1)};
        float sf[4] = {upk(Q01[jn], 0), upk(Q01[jn], 1), upk(Q23[jn], 0), upk(Q23[jn], 1)};
        float s2v[4];
#pragma unroll
        for (int r = 0; r < 4; ++r) {
            const int dd = i0 + r - j;
            const float pos = (float)(dd >= 0 ? dd : -dd);
            const float dist = sqrtf(fmaxf(sf[r] * rs1[r], 0.f) * pos);
            const float te = fmaxf(__expf(gneg * dist), 1e-5f);
            const float s2 = (sv[r] < -30000.f) ? NEGC : sv[r] * te;
            s2v[r] = s2;
            m2[r] = fmaxf(m2[r], s2);
        }
        P01[jn] = pk2(s2v[0], s2v[1]);
        P23[jn] = pk2(s2v[2], s2v[3]);
    }
#pragma unroll
    for (int r = 0; r < 4; ++r)
#pragma unroll
        for (int o = 1; o <= 8; o <<= 1) m2[r] = fmaxf(m2[r], __shfl_xor(m2[r], o));

    // ---- Phase 4: e2 + row sums, pack e2
    float sum2[4] = {0.f, 0.f, 0.f, 0.f};
#pragma unroll
    for (int jn = 0; jn < 32; ++jn) {
        float e[4];
        e[0] = __expf(upk(P01[jn], 0) - m2[0]);
        e[1] = __expf(upk(P01[jn], 1) - m2[1]);
        e[2] = __expf(upk(P23[jn], 0) - m2[2]);
        e[3] = __expf(upk(P23[jn], 1) - m2[3]);
#pragma unroll
        for (int r = 0; r < 4; ++r) sum2[r] += e[r];
        Q01[jn] = pk2(e[0], e[1]);
        Q23[jn] = pk2(e[2], e[3]);
    }
    float rs2[4];
#pragma unroll
    for (int r = 0; r < 4; ++r) {
#pragma unroll
        for (int o = 1; o <= 8; o <<= 1) sum2[r] += __shfl_xor(sum2[r], o);
        rs2[r] = 1.f / sum2[r];
    }

    // ---- Phase 5: PV via MFMA, two 256-wide chunks through LDS
    unsigned short* Pw = Pch[w];
    const unsigned short* vtb = Vt + (size_t)(b * Hdim + h) * DKdim * Sdim;
    f32x4 oacc[4] = {};
#pragma unroll 1
    for (int cc = 0; cc < 2; ++cc) {
#pragma unroll
        for (int jn2 = 0; jn2 < 16; ++jn2) {
            const int jn = cc * 16 + jn2;
            const int kl = jn2 * 16 + fr;
            Pw[(quad * 4 + 0) * PSTR + kl] = f2b(upk(Q01[jn], 0) * rs2[0]);
            Pw[(quad * 4 + 1) * PSTR + kl] = f2b(upk(Q01[jn], 1) * rs2[1]);
            Pw[(quad * 4 + 2) * PSTR + kl] = f2b(upk(Q23[jn], 0) * rs2[2]);
            Pw[(quad * 4 + 3) * PSTR + kl] = f2b(upk(Q23[jn], 1) * rs2[3]);
        }
        __syncthreads();
#pragma unroll
        for (int kt2 = 0; kt2 < 8; ++kt2) {
            const int kt = cc * 8 + kt2;
            frag16 pf = *(const frag16*)(Pw + fr * PSTR + kt2 * 32 + quad * 8);
#pragma unroll
            for (int dt = 0; dt < 4; ++dt) {
                frag16 vf = *(const frag16*)(vtb + (size_t)(dt * 16 + fr) * Sdim + kt * 32 + quad * 8);
                oacc[dt] = __builtin_amdgcn_mfma_f32_16x16x32_bf16(pf, vf, oacc[dt], 0, 0, 0);
            }
        }
        __syncthreads();
    }

    unsigned short* obase = Ob + ((size_t)(b * Sdim + q0)) * Ddim + h * DKdim;
#pragma unroll
    for (int dt = 0; dt < 4; ++dt)
#pragma unroll
        for (int r = 0; r < 4; ++r)
            obase[(size_t)(quad * 4 + r) * Ddim + dt * 16 + fr] = f2b(oacc[dt][r]);
}

// ---------------------------------------------------------------------------
// LayerNorm over last dim (512); fp32 out (nullable) + bf16 out (nullable).
// ---------------------------------------------------------------------------
__global__ __launch_bounds__(256) void ln_kernel(
    const float* __restrict__ X, const float* __restrict__ g,
    const float* __restrict__ bta, float* __restrict__ Y,
    unsigned short* __restrict__ Yb)
{
    const int row = blockIdx.x;
    const int t = threadIdx.x;
    __shared__ float r1[256], r2[256];
    const float* x = X + (size_t)row * Ddim;
    float a = x[t], b = x[t + 256];
    r1[t] = a + b;
    r2[t] = a * a + b * b;
    __syncthreads();
    for (int off = 128; off; off >>= 1) {
        if (t < off) { r1[t] += r1[t + off]; r2[t] += r2[t + off]; }
        __syncthreads();
    }
    float mean = r1[0] * (1.f / Ddim);
    float var = r2[0] * (1.f / Ddim) - mean * mean;
    float rs = rsqrtf(var + 1e-5f);
    float y0 = (a - mean) * rs * g[t] + bta[t];
    float y1 = (b - mean) * rs * g[t + 256] + bta[t + 256];
    if (Y) {
        float* y = Y + (size_t)row * Ddim;
        y[t] = y0;
        y[t + 256] = y1;
    }
    if (Yb) {
        unsigned short* yb = Yb + (size_t)row * Ddim;
        yb[t] = f2b(y0);
        yb[t + 256] = f2b(y1);
    }
}

// ---------------------------------------------------------------------------
extern "C" void kernel_launch(void* const* d_in, const int* in_sizes, int n_in,
                              void* d_out, int out_size, void* d_ws, size_t ws_size,
                              hipStream_t stream)
{
    const float* x0     = (const float*)d_in[0];
    const float* y0     = (const float*)d_in[1];
    const float* Wk     = (const float*)d_in[2];
    const float* bk     = (const float*)d_in[3];
    const float* Wv     = (const float*)d_in[4];
    const float* bv     = (const float*)d_in[5];
    const float* Wo     = (const float*)d_in[6];
    const float* bo     = (const float*)d_in[7];
    const float* gammas = (const float*)d_in[8];
    const float* ln1g   = (const float*)d_in[9];
    const float* ln1b   = (const float*)d_in[10];
    const float* W1     = (const float*)d_in[11];
    const float* b1     = (const float*)d_in[12];
    const float* W2     = (const float*)d_in[13];
    const float* b2     = (const float*)d_in[14];
    const float* ln2g   = (const float*)d_in[15];
    const float* ln2b   = (const float*)d_in[16];

    const size_t NBSD = (size_t)Mrows * Ddim;   // 4,194,304
    float* ws = (float*)d_ws;
    float* T1   = ws;
    float* X1   = T1 + NBSD;
    float* Xbuf = X1 + NBSD;
    unsigned short* Kbf = (unsigned short*)(Xbuf + NBSD);
    unsigned short* Vt  = Kbf + NBSD;
    unsigned short* AOb = Vt + NBSD;
    unsigned short* Abf = AOb + NBSD;
    unsigned short* Xbf = Abf + NBSD;
    unsigned short* Ybf = Xbf + NBSD;
    unsigned short* Hbb = Ybf + NBSD;                       // [M,F]
    unsigned short* WtAll = Hbb + (size_t)Mrows * Fdim;     // 6.55M bf16

    // transposed-weight offsets
    auto WtK = [&](int l) { return WtAll + (size_t)(l * 3 + 0) * 262144; };
    auto WtV = [&](int l) { return WtAll + (size_t)(l * 3 + 1) * 262144; };
    auto WtO = [&](int l) { return WtAll + (size_t)(l * 3 + 2) * 262144; };
    auto Wt1 = [&](int l) { return WtAll + 9 * 262144 + (size_t)(l >> 1) * (512 * 2048); };
    auto Wt2 = [&](int l) { return WtAll + 9 * 262144 + 2 * (512 * 2048) + (size_t)(l >> 1) * (2048 * 512); };

    const int convBlocks = (int)(NBSD / 2048);

    wtrans_all<<<1600, 256, 0, stream>>>(Wk, Wv, Wo, W1, W2, WtAll);

    auto run_block = [&](int l, const float* qinf, const unsigned short* qinb,
                         const unsigned short* vinb, int mask_type, bool ffn,
                         float* outf, unsigned short* outb) {
        const float* bk_l = bk + (size_t)l * Ddim;
        const float* bv_l = bv + (size_t)l * Ddim;
        const float* bo_l = bo + (size_t)l * Ddim;

        // K (=Q) + V projections in one launch (z=0: K->Kbf, z=1: V->Vt)
        gemm_n64<<<dim3(8, 64, 2), 256, 0, stream>>>(
            qinb, vinb, WtK(l), WtV(l), bk_l, bv_l,
            nullptr, nullptr, Kbf, Vt, Ddim);
        // attention
        attn_v3<<<dim3(Sdim / 64, Hdim, Bdim), 256, 0, stream>>>(
            Kbf, Vt, gammas + (size_t)l * Hdim, AOb, mask_type);
        // O-projection + residual -> T1 (fp32); LN1
        gemm_n64<<<dim3(8, 64, 1), 256, 0, stream>>>(
            AOb, AOb, WtO(l), WtO(l), bo_l, bo_l,
            qinf, T1, nullptr, nullptr, Ddim);
        float* x1f = ffn ? X1 : outf;
        unsigned short* x1b = ffn ? Abf : outb;
        ln_kernel<<<Mrows, 256, 0, stream>>>(T1,
            ln1g + (size_t)l * Ddim, ln1b + (size_t)l * Ddim, x1f, x1b);
        if (ffn) {
            const float* b1_l = b1 + (size_t)l * Fdim;
            const float* b2_l = b2 + (size_t)l * Ddim;
            gemm_mfma<<<dim3(Fdim / 128, Mrows / 128), 256, 0, stream>>>(
                (const __hip_bfloat16*)Abf, (const __hip_bfloat16*)Wt1(l),
                b1_l, nullptr, nullptr, Hbb, Mrows, Fdim, Ddim, 1);
            gemm_n64<<<dim3(8, 64, 1), 256, 0, stream>>>(
                Hbb, Hbb, Wt2(l), Wt2(l), b2_l, b2_l,
                X1, T1, nullptr, nullptr, Fdim);
            ln_kernel<<<Mrows, 256, 0, stream>>>(T1,
                ln2g + (size_t)l * Ddim, ln2b + (size_t)l * Ddim, outf, outb);
        }
    };

    // Block 0: knowledge encoder (y), mask1, FFN -> Ybf (bf16 only)
    conv_b<<<convBlocks, 256, 0, stream>>>(y0, Abf);
    run_block(0, y0, Abf, Abf, 1, true, nullptr, Ybf);
    // Block 1: question encoder (x), mask1, no FFN -> Xbuf/Xbf
    conv_b<<<convBlocks, 256, 0, stream>>>(x0, Abf);
    run_block(1, x0, Abf, Abf, 1, false, Xbuf, Xbf);
    // Block 2: knowledge retriever, q/k=x, v=y, mask0, FFN -> d_out (fp32)
    run_block(2, Xbuf, Xbf, Ybf, 0, true, (float*)d_out, nullptr);
}

// Round 8
// 819.121 us; speedup vs baseline: 1.5414x; 1.5414x over previous
//
#include <hip/hip_runtime.h>
#include <hip/hip_bf16.h>

// Problem dims (fixed)
#define Bdim 16
#define Sdim 512
#define Ddim 512
#define Hdim 8
#define DKdim 64
#define Fdim 2048
#define Mrows (Bdim * Sdim)   // 8192

typedef __attribute__((ext_vector_type(8))) short  frag16;   // 8 bf16 (4 VGPRs)
typedef __attribute__((ext_vector_type(4))) float  f32x4;    // MFMA acc
typedef __attribute__((ext_vector_type(8))) unsigned short ushort8;
typedef __attribute__((ext_vector_type(4))) unsigned short ushort4v;

// round-to-nearest-even fp32 -> bf16 (finite data)
__device__ __forceinline__ unsigned short f2b(float x) {
    union { float f; unsigned int u; } v; v.f = x;
    unsigned int r = (v.u + 0x7FFFu + ((v.u >> 16) & 1u)) >> 16;
    return (unsigned short)r;
}

// ---------------------------------------------------------------------------
// bf16 MFMA GEMM, 128x128 tile (used for FFN1, N=2048)
// ---------------------------------------------------------------------------
__global__ __launch_bounds__(256) void gemm_mfma(
    const __hip_bfloat16* __restrict__ A, const __hip_bfloat16* __restrict__ Bt,
    const float* __restrict__ bias, const float* __restrict__ R,
    float* __restrict__ Cf, unsigned short* __restrict__ Cb,
    int M, int N, int K, int do_relu)
{
    __shared__ short As[128 * 32];
    __shared__ short Bs[128 * 32];

    const int t = threadIdx.x;
    const int lane = t & 63;
    const int wave = t >> 6;
    const int bm = blockIdx.y * 128;
    const int bn = blockIdx.x * 128;
    const int wm = (wave >> 1) * 64;
    const int wn = (wave & 1) * 64;

    f32x4 acc[4][4] = {};
    const int lrow = lane >> 2;
    const int lcol = (lane & 3) * 8;

    for (int k0 = 0; k0 < K; k0 += 32) {
#pragma unroll
        for (int i = 0; i < 2; ++i) {
            const int chunk = wave * 2 + i;
            const int row = chunk * 16 + lrow;
            const __hip_bfloat16* ga = A + (size_t)(bm + row) * K + k0 + lcol;
            const __hip_bfloat16* gb = Bt + (size_t)(bn + row) * K + k0 + lcol;
            __builtin_amdgcn_global_load_lds(
                (const __attribute__((address_space(1))) unsigned int*)ga,
                (__attribute__((address_space(3))) unsigned int*)(As + chunk * 512),
                16, 0, 0);
            __builtin_amdgcn_global_load_lds(
                (const __attribute__((address_space(1))) unsigned int*)gb,
                (__attribute__((address_space(3))) unsigned int*)(Bs + chunk * 512),
                16, 0, 0);
        }
        __syncthreads();

        const int fr = lane & 15;
        const int quad = lane >> 4;
        frag16 af[4], bfr[4];
#pragma unroll
        for (int i = 0; i < 4; ++i) {
            af[i]  = *(const frag16*)(As + (wm + i * 16 + fr) * 32 + quad * 8);
            bfr[i] = *(const frag16*)(Bs + (wn + i * 16 + fr) * 32 + quad * 8);
        }
#pragma unroll
        for (int mi = 0; mi < 4; ++mi)
#pragma unroll
            for (int ni = 0; ni < 4; ++ni)
                acc[mi][ni] = __builtin_amdgcn_mfma_f32_16x16x32_bf16(
                    af[mi], bfr[ni], acc[mi][ni], 0, 0, 0);
        __syncthreads();
    }

    const int fr = lane & 15;
    const int quad = lane >> 4;
#pragma unroll
    for (int mi = 0; mi < 4; ++mi) {
#pragma unroll
        for (int r = 0; r < 4; ++r) {
            const int m = bm + wm + mi * 16 + quad * 4 + r;
#pragma unroll
            for (int ni = 0; ni < 4; ++ni) {
                const int n = bn + wn + ni * 16 + fr;
                float v = acc[mi][ni][r] + bias[n];
                if (R) v += R[(size_t)m * N + n];
                if (do_relu) v = fmaxf(v, 0.f);
                if (Cf) Cf[(size_t)m * N + n] = v;
                if (Cb) Cb[(size_t)m * N + n] = f2b(v);
            }
        }
    }
}

// ---------------------------------------------------------------------------
// bf16 MFMA GEMM, 128x64 tile, N=512 fixed. Dual-mode via blockIdx.z:
// z=0: A0@B0^T+bias0 -> Cb (normal bf16) / Cf(+R) fp32
// z=1: A1@B1^T+bias1 -> CbT transposed Vt[b,h,d,s] bf16
// ---------------------------------------------------------------------------
__global__ __launch_bounds__(256) void gemm_n64(
    const unsigned short* __restrict__ A0, const unsigned short* __restrict__ A1,
    const unsigned short* __restrict__ B0, const unsigned short* __restrict__ B1,
    const float* __restrict__ bias0, const float* __restrict__ bias1,
    const float* __restrict__ R, float* __restrict__ Cf,
    unsigned short* __restrict__ Cb, unsigned short* __restrict__ CbT,
    int K)
{
    const int NN = 512;
    __shared__ short As[128 * 32];
    __shared__ short Bs[64 * 32];

    const int trans = blockIdx.z;
    const unsigned short* A  = trans ? A1 : A0;
    const unsigned short* Bt = trans ? B1 : B0;
    const float* bias        = trans ? bias1 : bias0;

    const int t = threadIdx.x;
    const int lane = t & 63;
    const int wave = t >> 6;
    const int bm = blockIdx.y * 128;
    const int bn = blockIdx.x * 64;
    const int wm = (wave >> 1) * 64;
    const int wn = (wave & 1) * 32;

    f32x4 acc[4][2] = {};
    const int lrow = lane >> 2;
    const int lcol = (lane & 3) * 8;

    for (int k0 = 0; k0 < K; k0 += 32) {
#pragma unroll
        for (int i = 0; i < 2; ++i) {
            const int chunk = wave * 2 + i;
            const int row = chunk * 16 + lrow;
            const unsigned short* ga = A + (size_t)(bm + row) * K + k0 + lcol;
            __builtin_amdgcn_global_load_lds(
                (const __attribute__((address_space(1))) unsigned int*)ga,
                (__attribute__((address_space(3))) unsigned int*)(As + chunk * 512),
                16, 0, 0);
        }
        {
            const int row = wave * 16 + lrow;
            const unsigned short* gb = Bt + (size_t)(bn + row) * K + k0 + lcol;
            __builtin_amdgcn_global_load_lds(
                (const __attribute__((address_space(1))) unsigned int*)gb,
                (__attribute__((address_space(3))) unsigned int*)(Bs + wave * 512),
                16, 0, 0);
        }
        __syncthreads();

        const int fr = lane & 15;
        const int quad = lane >> 4;
        frag16 af[4], bfr[2];
#pragma unroll
        for (int i = 0; i < 4; ++i)
            af[i] = *(const frag16*)(As + (wm + i * 16 + fr) * 32 + quad * 8);
#pragma unroll
        for (int i = 0; i < 2; ++i)
            bfr[i] = *(const frag16*)(Bs + (wn + i * 16 + fr) * 32 + quad * 8);
#pragma unroll
        for (int mi = 0; mi < 4; ++mi)
#pragma unroll
            for (int ni = 0; ni < 2; ++ni)
                acc[mi][ni] = __builtin_amdgcn_mfma_f32_16x16x32_bf16(
                    af[mi], bfr[ni], acc[mi][ni], 0, 0, 0);
        __syncthreads();
    }

    const int fr = lane & 15;
    const int quad = lane >> 4;

    if (trans) {
#pragma unroll
        for (int mi = 0; mi < 4; ++mi)
#pragma unroll
            for (int ni = 0; ni < 2; ++ni) {
                const int m = bm + wm + mi * 16 + quad * 4;
                const int n = bn + wn + ni * 16 + fr;
                ushort4v o;
#pragma unroll
                for (int r = 0; r < 4; ++r) o[r] = f2b(acc[mi][ni][r] + bias[n]);
                const int bb = m >> 9, s = m & 511;
                const int hh = n >> 6, dd = n & 63;
                *(ushort4v*)(CbT + (((size_t)((bb * Hdim + hh) * DKdim + dd)) << 9) + s) = o;
            }
        return;
    }

#pragma unroll
    for (int mi = 0; mi < 4; ++mi) {
#pragma unroll
        for (int r = 0; r < 4; ++r) {
            const int m = bm + wm + mi * 16 + quad * 4 + r;
#pragma unroll
            for (int ni = 0; ni < 2; ++ni) {
                const int n = bn + wn + ni * 16 + fr;
                float v = acc[mi][ni][r] + bias[n];
                if (R) v += R[(size_t)m * NN + n];
                if (Cf) Cf[(size_t)m * NN + n] = v;
                if (Cb) Cb[(size_t)m * NN + n] = f2b(v);
            }
        }
    }
}

// ---------------------------------------------------------------------------
// fp32 -> bf16 convert
// ---------------------------------------------------------------------------
__global__ __launch_bounds__(256) void conv_b(
    const float* __restrict__ X, unsigned short* __restrict__ Y)
{
    const size_t i = ((size_t)blockIdx.x * 256 + threadIdx.x) * 8;
    float4 a = *(const float4*)(X + i);
    float4 b = *(const float4*)(X + i + 4);
    ushort8 o;
    o[0] = f2b(a.x); o[1] = f2b(a.y); o[2] = f2b(a.z); o[3] = f2b(a.w);
    o[4] = f2b(b.x); o[5] = f2b(b.y); o[6] = f2b(b.z); o[7] = f2b(b.w);
    *(ushort8*)(Y + i) = o;
}

// ---------------------------------------------------------------------------
// ALL weight transposes fused: 1600 tiles of 64x64, [K,N] fp32 -> [N,K] bf16
// ---------------------------------------------------------------------------
__global__ __launch_bounds__(256) void wtrans_all(
    const float* __restrict__ Wk, const float* __restrict__ Wv,
    const float* __restrict__ Wo, const float* __restrict__ W1,
    const float* __restrict__ W2, unsigned short* __restrict__ dst)
{
    const int bid = blockIdx.x;
    const float* src; unsigned short* d; int K, N, tk, tn;
    if (bid < 576) {
        const int mat = bid >> 6, tile = bid & 63;
        const int l = mat / 3, wch = mat % 3;
        const float* W = (wch == 0) ? Wk : (wch == 1) ? Wv : Wo;
        src = W + (size_t)l * 262144;
        d = dst + (size_t)mat * 262144;
        K = 512; N = 512; tn = tile & 7; tk = tile >> 3;
    } else if (bid < 1088) {
        const int idx = bid - 576, l2 = idx >> 8, tile = idx & 255;
        src = W1 + (size_t)(l2 * 2) * (512 * 2048);
        d = dst + 9 * 262144 + (size_t)l2 * (512 * 2048);
        K = 512; N = 2048; tn = tile & 31; tk = tile >> 5;
    } else {
        const int idx = bid - 1088, l2 = idx >> 8, tile = idx & 255;
        src = W2 + (size_t)(l2 * 2) * (2048 * 512);
        d = dst + 9 * 262144 + 2 * (512 * 2048) + (size_t)l2 * (2048 * 512);
        K = 2048; N = 512; tn = tile & 7; tk = tile >> 3;
    }
    const int n0 = tn * 64, k0 = tk * 64;
    __shared__ float T[64][65];
    const int t = threadIdx.x;
    const int kl = t >> 4, n4 = (t & 15) << 2;
#pragma unroll
    for (int it = 0; it < 4; ++it) {
        const int k = kl + it * 16;
        float4 v = *(const float4*)(src + (size_t)(k0 + k) * N + n0 + n4);
        T[n4 + 0][k] = v.x; T[n4 + 1][k] = v.y;
        T[n4 + 2][k] = v.z; T[n4 + 3][k] = v.w;
    }
    __syncthreads();
    const int nl = t >> 3, k8 = (t & 7) << 3;
#pragma unroll
    for (int it = 0; it < 2; ++it) {
        const int n = nl + it * 32;
        ushort8 o;
#pragma unroll
        for (int c = 0; c < 8; ++c) o[c] = f2b(T[n][k8 + c]);
        *(ushort8*)(d + (size_t)(n0 + n) * K + k0 + k8) = o;
    }
}

// ---------------------------------------------------------------------------
// Flash-style monotonic attention. One wave = 16 q-rows, no inter-wave sync.
// Pass 1: QK MFMA sweep -> sum1 = sum(valid e^s).
// Pass 2: stream j-tiles high->low: QK MFMA again, strict suffix via shfl
// scan, decay, e2 unnormalized (exact 0 for invalid); P staged bf16 -> PV
// MFMA every 2 tiles. Fully-masked row (mask0, i==0): reference semantics =
// uniform 1/512 over ALL j -> that wave sweeps all tiles with e2=1.
// ---------------------------------------------------------------------------
__global__ __launch_bounds__(256, 4) void attn_flash(
    const unsigned short* __restrict__ Kb,   // [B*S, D] bf16 (Q == K)
    const unsigned short* __restrict__ Vt,   // [B,H,DK,S] bf16
    const float* __restrict__ gam,
    unsigned short* __restrict__ Ob,         // [B*S, D] bf16
    int mask_type)
{
    __shared__ unsigned short Pst[4][16 * 36];   // per-wave P staging, stride 36

    const int qt = blockIdx.x, h = blockIdx.y, b = blockIdx.z;
    const int t = threadIdx.x, lane = t & 63, w = t >> 6;
    const int quad = lane >> 4, fr = lane & 15;
    const int q0 = qt * 64 + w * 16;
    const int i0 = q0 + quad * 4;            // this lane's 4 q-rows

    const unsigned short* kbase = Kb + (size_t)b * Sdim * Ddim + h * DKdim;

    frag16 aq0 = *(const frag16*)(kbase + (size_t)(q0 + fr) * Ddim + quad * 8);
    frag16 aq1 = *(const frag16*)(kbase + (size_t)(q0 + fr) * Ddim + 32 + quad * 8);

    // ---- Pass 1: sum1 per row (no max-subtraction; |s| small)
    const int jnmax = (q0 + 15) >> 4;
    float sum1[4] = {0.f, 0.f, 0.f, 0.f};
    for (int jn = 0; jn <= jnmax; ++jn) {
        frag16 b0 = *(const frag16*)(kbase + (size_t)(jn * 16 + fr) * Ddim + quad * 8);
        frag16 b1 = *(const frag16*)(kbase + (size_t)(jn * 16 + fr) * Ddim + 32 + quad * 8);
        f32x4 z = {0.f, 0.f, 0.f, 0.f};
        z = __builtin_amdgcn_mfma_f32_16x16x32_bf16(aq0, b0, z, 0, 0, 0);
        z = __builtin_amdgcn_mfma_f32_16x16x32_bf16(aq1, b1, z, 0, 0, 0);
        const int j = jn * 16 + fr;
#pragma unroll
        for (int r = 0; r < 4; ++r) {
            const bool valid = mask_type ? (j <= i0 + r) : (j < i0 + r);
            sum1[r] += valid ? __expf(z[r] * 0.125f) : 0.f;
        }
    }
#pragma unroll
    for (int r = 0; r < 4; ++r) {
#pragma unroll
        for (int o = 1; o <= 8; o <<= 1) sum1[r] += __shfl_xor(sum1[r], o);
    }
    float rsum1[4];
#pragma unroll
    for (int r = 0; r < 4; ++r) rsum1[r] = 1.f / sum1[r];   // inf iff fully masked

    const float gneg = -log1pf(__expf(gam[h]));   // -softplus(gamma)

    // ---- Pass 2: stream tiles high->low with suffix scan + online PV
    // Fully-masked-row wave (mask0, q0==0) must cover ALL tiles for its
    // uniform-over-512 row; its other rows get e2=0 beyond their diagonal.
    unsigned short* Pw = Pst[w];
    const unsigned short* vtb = Vt + (size_t)(b * Hdim + h) * DKdim * Sdim;
    const bool fm_wave = (mask_type == 0) && (q0 == 0);
    const int umax = fm_wave ? (Sdim / 32 - 1) : ((q0 + 15) >> 5);
    float U[4] = {0.f, 0.f, 0.f, 0.f};
    float sum2[4] = {0.f, 0.f, 0.f, 0.f};
    f32x4 oacc[4] = {};

    for (int u = umax; u >= 0; --u) {
#pragma unroll
        for (int half = 1; half >= 0; --half) {
            const int jn = 2 * u + half;
            frag16 b0 = *(const frag16*)(kbase + (size_t)(jn * 16 + fr) * Ddim + quad * 8);
            frag16 b1 = *(const frag16*)(kbase + (size_t)(jn * 16 + fr) * Ddim + 32 + quad * 8);
            f32x4 z = {0.f, 0.f, 0.f, 0.f};
            z = __builtin_amdgcn_mfma_f32_16x16x32_bf16(aq0, b0, z, 0, 0, 0);
            z = __builtin_amdgcn_mfma_f32_16x16x32_bf16(aq1, b1, z, 0, 0, 0);
            const int j = jn * 16 + fr;
#pragma unroll
            for (int r = 0; r < 4; ++r) {
                const int i = i0 + r;
                const bool valid = mask_type ? (j <= i) : (j < i);
                const bool fmrow = (mask_type == 0) && (i == 0);
                const float s = z[r] * 0.125f;
                const float e1 = valid ? __expf(s) : 0.f;
                // strict suffix within tile (over fr = j-within-tile)
                float incl = e1;
#pragma unroll
                for (int o = 1; o <= 8; o <<= 1) {
                    const float v = __shfl_down(incl, o);
                    incl += (fr + o < 16) ? v : 0.f;
                }
                const float Tt = __shfl(incl, lane & 48);   // fr=0 holds tile total
                const float suf = U[r] + (incl - e1);       // strict global suffix
                U[r] += Tt;
                const int dd = i - j;
                const float pos = (float)(dd >= 0 ? dd : -dd);
                const float ratio = suf * rsum1[r];
                const float arg = (ratio > 0.f) ? ratio * pos : 0.f;  // NaN-safe
                const float dist = sqrtf(arg);
                const float te = fminf(fmaxf(__expf(gneg * dist), 1e-5f), 1e5f);
                const float e2 = valid ? __expf(s * te) : (fmrow ? 1.f : 0.f);
                sum2[r] += e2;
                Pw[(quad * 4 + r) * 36 + half * 16 + fr] = f2b(e2);
            }
        }
        // PV over this pair's 32-wide j window (A from LDS, B from Vt)
        frag16 pf = *(const frag16*)(Pw + fr * 36 + quad * 8);
        const int jb = u * 32;
#pragma unroll
        for (int dt = 0; dt < 4; ++dt) {
            frag16 vf = *(const frag16*)(vtb + (size_t)(dt * 16 + fr) * Sdim + jb + quad * 8);
            oacc[dt] = __builtin_amdgcn_mfma_f32_16x16x32_bf16(pf, vf, oacc[dt], 0, 0, 0);
        }
    }

    float rs2[4];
#pragma unroll
    for (int r = 0; r < 4; ++r) {
#pragma unroll
        for (int o = 1; o <= 8; o <<= 1) sum2[r] += __shfl_xor(sum2[r], o);
        rs2[r] = 1.f / sum2[r];
    }

    unsigned short* obase = Ob + ((size_t)(b * Sdim + q0)) * Ddim + h * DKdim;
#pragma unroll
    for (int dt = 0; dt < 4; ++dt)
#pragma unroll
        for (int r = 0; r < 4; ++r)
            obase[(size_t)(quad * 4 + r) * Ddim + dt * 16 + fr] = f2b(oacc[dt][r] * rs2[r]);
}

// ---------------------------------------------------------------------------
// LayerNorm over last dim (512); fp32 out (nullable) + bf16 out (nullable).
// ---------------------------------------------------------------------------
__global__ __launch_bounds__(256) void ln_kernel(
    const float* __restrict__ X, const float* __restrict__ g,
    const float* __restrict__ bta, float* __restrict__ Y,
    unsigned short* __restrict__ Yb)
{
    const int row = blockIdx.x;
    const int t = threadIdx.x;
    __shared__ float r1[256], r2[256];
    const float* x = X + (size_t)row * Ddim;
    float a = x[t], b = x[t + 256];
    r1[t] = a + b;
    r2[t] = a * a + b * b;
    __syncthreads();
    for (int off = 128; off; off >>= 1) {
        if (t < off) { r1[t] += r1[t + off]; r2[t] += r2[t + off]; }
        __syncthreads();
    }
    float mean = r1[0] * (1.f / Ddim);
    float var = r2[0] * (1.f / Ddim) - mean * mean;
    float rs = rsqrtf(var + 1e-5f);
    float y0 = (a - mean) * rs * g[t] + bta[t];
    float y1 = (b - mean) * rs * g[t + 256] + bta[t + 256];
    if (Y) {
        float* y = Y + (size_t)row * Ddim;
        y[t] = y0;
        y[t + 256] = y1;
    }
    if (Yb) {
        unsigned short* yb = Yb + (size_t)row * Ddim;
        yb[t] = f2b(y0);
        yb[t + 256] = f2b(y1);
    }
}

// ---------------------------------------------------------------------------
extern "C" void kernel_launch(void* const* d_in, const int* in_sizes, int n_in,
                              void* d_out, int out_size, void* d_ws, size_t ws_size,
                              hipStream_t stream)
{
    const float* x0     = (const float*)d_in[0];
    const float* y0     = (const float*)d_in[1];
    const float* Wk     = (const float*)d_in[2];
    const float* bk     = (const float*)d_in[3];
    const float* Wv     = (const float*)d_in[4];
    const float* bv     = (const float*)d_in[5];
    const float* Wo     = (const float*)d_in[6];
    const float* bo     = (const float*)d_in[7];
    const float* gammas = (const float*)d_in[8];
    const float* ln1g   = (const float*)d_in[9];
    const float* ln1b   = (const float*)d_in[10];
    const float* W1     = (const float*)d_in[11];
    const float* b1     = (const float*)d_in[12];
    const float* W2     = (const float*)d_in[13];
    const float* b2     = (const float*)d_in[14];
    const float* ln2g   = (const float*)d_in[15];
    const float* ln2b   = (const float*)d_in[16];

    const size_t NBSD = (size_t)Mrows * Ddim;   // 4,194,304
    float* ws = (float*)d_ws;
    float* T1   = ws;
    float* X1   = T1 + NBSD;
    float* Xbuf = X1 + NBSD;
    unsigned short* Kbf = (unsigned short*)(Xbuf + NBSD);
    unsigned short* Vt  = Kbf + NBSD;
    unsigned short* AOb = Vt + NBSD;
    unsigned short* Abf = AOb + NBSD;
    unsigned short* Xbf = Abf + NBSD;
    unsigned short* Ybf = Xbf + NBSD;
    unsigned short* Hbb = Ybf + NBSD;                       // [M,F]
    unsigned short* WtAll = Hbb + (size_t)Mrows * Fdim;

    auto WtK = [&](int l) { return WtAll + (size_t)(l * 3 + 0) * 262144; };
    auto WtV = [&](int l) { return WtAll + (size_t)(l * 3 + 1) * 262144; };
    auto WtO = [&](int l) { return WtAll + (size_t)(l * 3 + 2) * 262144; };
    auto Wt1 = [&](int l) { return WtAll + 9 * 262144 + (size_t)(l >> 1) * (512 * 2048); };
    auto Wt2 = [&](int l) { return WtAll + 9 * 262144 + 2 * (512 * 2048) + (size_t)(l >> 1) * (2048 * 512); };

    const int convBlocks = (int)(NBSD / 2048);

    wtrans_all<<<1600, 256, 0, stream>>>(Wk, Wv, Wo, W1, W2, WtAll);

    auto run_block = [&](int l, const float* qinf, const unsigned short* qinb,
                         const unsigned short* vinb, int mask_type, bool ffn,
                         float* outf, unsigned short* outb) {
        const float* bk_l = bk + (size_t)l * Ddim;
        const float* bv_l = bv + (size_t)l * Ddim;
        const float* bo_l = bo + (size_t)l * Ddim;

        // K (=Q) + V projections in one launch (z=0: K->Kbf, z=1: V->Vt)
        gemm_n64<<<dim3(8, 64, 2), 256, 0, stream>>>(
            qinb, vinb, WtK(l), WtV(l), bk_l, bv_l,
            nullptr, nullptr, Kbf, Vt, Ddim);
        // attention (flash-style streaming)
        attn_flash<<<dim3(Sdim / 64, Hdim, Bdim), 256, 0, stream>>>(
            Kbf, Vt, gammas + (size_t)l * Hdim, AOb, mask_type);
        // O-projection + residual -> T1 (fp32); LN1
        gemm_n64<<<dim3(8, 64, 1), 256, 0, stream>>>(
            AOb, AOb, WtO(l), WtO(l), bo_l, bo_l,
            qinf, T1, nullptr, nullptr, Ddim);
        float* x1f = ffn ? X1 : outf;
        unsigned short* x1b = ffn ? Abf : outb;
        ln_kernel<<<Mrows, 256, 0, stream>>>(T1,
            ln1g + (size_t)l * Ddim, ln1b + (size_t)l * Ddim, x1f, x1b);
        if (ffn) {
            const float* b1_l = b1 + (size_t)l * Fdim;
            const float* b2_l = b2 + (size_t)l * Ddim;
            gemm_mfma<<<dim3(Fdim / 128, Mrows / 128), 256, 0, stream>>>(
                (const __hip_bfloat16*)Abf, (const __hip_bfloat16*)Wt1(l),
                b1_l, nullptr, nullptr, Hbb, Mrows, Fdim, Ddim, 1);
            gemm_n64<<<dim3(8, 64, 1), 256, 0, stream>>>(
                Hbb, Hbb, Wt2(l), Wt2(l), b2_l, b2_l,
                X1, T1, nullptr, nullptr, Fdim);
            ln_kernel<<<Mrows, 256, 0, stream>>>(T1,
                ln2g + (size_t)l * Ddim, ln2b + (size_t)l * Ddim, outf, outb);
        }
    };

    // Block 0: knowledge encoder (y), mask1, FFN -> Ybf (bf16 only)
    conv_b<<<convBlocks, 256, 0, stream>>>(y0, Abf);
    run_block(0, y0, Abf, Abf, 1, true, nullptr, Ybf);
    // Block 1: question encoder (x), mask1, no FFN -> Xbuf/Xbf
    conv_b<<<convBlocks, 256, 0, stream>>>(x0, Abf);
    run_block(1, x0, Abf, Abf, 1, false, Xbuf, Xbf);
    // Block 2: knowledge retriever, q/k=x, v=y, mask0, FFN -> d_out (fp32)
    run_block(2, Xbuf, Xbf, Ybf, 0, true, (float*)d_out, nullptr);
}

// Round 9
// 721.443 us; speedup vs baseline: 1.7501x; 1.1354x over previous
//
#include <hip/hip_runtime.h>
#include <hip/hip_bf16.h>

// Problem dims (fixed)
#define Bdim 16
#define Sdim 512
#define Ddim 512
#define Hdim 8
#define DKdim 64
#define Fdim 2048
#define Mrows (Bdim * Sdim)   // 8192

typedef __attribute__((ext_vector_type(8))) short  frag16;   // 8 bf16 (4 VGPRs)
typedef __attribute__((ext_vector_type(4))) float  f32x4;    // MFMA acc
typedef __attribute__((ext_vector_type(8))) unsigned short ushort8;
typedef __attribute__((ext_vector_type(4))) unsigned short ushort4v;

// round-to-nearest-even fp32 -> bf16 (finite data)
__device__ __forceinline__ unsigned short f2b(float x) {
    union { float f; unsigned int u; } v; v.f = x;
    unsigned int r = (v.u + 0x7FFFu + ((v.u >> 16) & 1u)) >> 16;
    return (unsigned short)r;
}

// ---------------------------------------------------------------------------
// bf16 MFMA GEMM, 128x128 tile (used for FFN1, N=2048)
// ---------------------------------------------------------------------------
__global__ __launch_bounds__(256) void gemm_mfma(
    const __hip_bfloat16* __restrict__ A, const __hip_bfloat16* __restrict__ Bt,
    const float* __restrict__ bias, const float* __restrict__ R,
    float* __restrict__ Cf, unsigned short* __restrict__ Cb,
    int M, int N, int K, int do_relu)
{
    __shared__ short As[128 * 32];
    __shared__ short Bs[128 * 32];

    const int t = threadIdx.x;
    const int lane = t & 63;
    const int wave = t >> 6;
    const int bm = blockIdx.y * 128;
    const int bn = blockIdx.x * 128;
    const int wm = (wave >> 1) * 64;
    const int wn = (wave & 1) * 64;

    f32x4 acc[4][4] = {};
    const int lrow = lane >> 2;
    const int lcol = (lane & 3) * 8;

    for (int k0 = 0; k0 < K; k0 += 32) {
#pragma unroll
        for (int i = 0; i < 2; ++i) {
            const int chunk = wave * 2 + i;
            const int row = chunk * 16 + lrow;
            const __hip_bfloat16* ga = A + (size_t)(bm + row) * K + k0 + lcol;
            const __hip_bfloat16* gb = Bt + (size_t)(bn + row) * K + k0 + lcol;
            __builtin_amdgcn_global_load_lds(
                (const __attribute__((address_space(1))) unsigned int*)ga,
                (__attribute__((address_space(3))) unsigned int*)(As + chunk * 512),
                16, 0, 0);
            __builtin_amdgcn_global_load_lds(
                (const __attribute__((address_space(1))) unsigned int*)gb,
                (__attribute__((address_space(3))) unsigned int*)(Bs + chunk * 512),
                16, 0, 0);
        }
        __syncthreads();

        const int fr = lane & 15;
        const int quad = lane >> 4;
        frag16 af[4], bfr[4];
#pragma unroll
        for (int i = 0; i < 4; ++i) {
            af[i]  = *(const frag16*)(As + (wm + i * 16 + fr) * 32 + quad * 8);
            bfr[i] = *(const frag16*)(Bs + (wn + i * 16 + fr) * 32 + quad * 8);
        }
#pragma unroll
        for (int mi = 0; mi < 4; ++mi)
#pragma unroll
            for (int ni = 0; ni < 4; ++ni)
                acc[mi][ni] = __builtin_amdgcn_mfma_f32_16x16x32_bf16(
                    af[mi], bfr[ni], acc[mi][ni], 0, 0, 0);
        __syncthreads();
    }

    const int fr = lane & 15;
    const int quad = lane >> 4;
#pragma unroll
    for (int mi = 0; mi < 4; ++mi) {
#pragma unroll
        for (int r = 0; r < 4; ++r) {
            const int m = bm + wm + mi * 16 + quad * 4 + r;
#pragma unroll
            for (int ni = 0; ni < 4; ++ni) {
                const int n = bn + wn + ni * 16 + fr;
                float v = acc[mi][ni][r] + bias[n];
                if (R) v += R[(size_t)m * N + n];
                if (do_relu) v = fmaxf(v, 0.f);
                if (Cf) Cf[(size_t)m * N + n] = v;
                if (Cb) Cb[(size_t)m * N + n] = f2b(v);
            }
        }
    }
}

// ---------------------------------------------------------------------------
// bf16 MFMA GEMM, 128x64 tile, N=512 fixed. Dual-mode via blockIdx.z:
// z=0: A0@B0^T+bias0 -> Cb (normal bf16) / Cf(+R) fp32
// z=1: A1@B1^T+bias1 -> CbT transposed Vt[b,h,d,s] bf16
// ---------------------------------------------------------------------------
__global__ __launch_bounds__(256) void gemm_n64(
    const unsigned short* __restrict__ A0, const unsigned short* __restrict__ A1,
    const unsigned short* __restrict__ B0, const unsigned short* __restrict__ B1,
    const float* __restrict__ bias0, const float* __restrict__ bias1,
    const float* __restrict__ R, float* __restrict__ Cf,
    unsigned short* __restrict__ Cb, unsigned short* __restrict__ CbT,
    int K)
{
    const int NN = 512;
    __shared__ short As[128 * 32];
    __shared__ short Bs[64 * 32];

    const int trans = blockIdx.z;
    const unsigned short* A  = trans ? A1 : A0;
    const unsigned short* Bt = trans ? B1 : B0;
    const float* bias        = trans ? bias1 : bias0;

    const int t = threadIdx.x;
    const int lane = t & 63;
    const int wave = t >> 6;
    const int bm = blockIdx.y * 128;
    const int bn = blockIdx.x * 64;
    const int wm = (wave >> 1) * 64;
    const int wn = (wave & 1) * 32;

    f32x4 acc[4][2] = {};
    const int lrow = lane >> 2;
    const int lcol = (lane & 3) * 8;

    for (int k0 = 0; k0 < K; k0 += 32) {
#pragma unroll
        for (int i = 0; i < 2; ++i) {
            const int chunk = wave * 2 + i;
            const int row = chunk * 16 + lrow;
            const unsigned short* ga = A + (size_t)(bm + row) * K + k0 + lcol;
            __builtin_amdgcn_global_load_lds(
                (const __attribute__((address_space(1))) unsigned int*)ga,
                (__attribute__((address_space(3))) unsigned int*)(As + chunk * 512),
                16, 0, 0);
        }
        {
            const int row = wave * 16 + lrow;
            const unsigned short* gb = Bt + (size_t)(bn + row) * K + k0 + lcol;
            __builtin_amdgcn_global_load_lds(
                (const __attribute__((address_space(1))) unsigned int*)gb,
                (__attribute__((address_space(3))) unsigned int*)(Bs + wave * 512),
                16, 0, 0);
        }
        __syncthreads();

        const int fr = lane & 15;
        const int quad = lane >> 4;
        frag16 af[4], bfr[2];
#pragma unroll
        for (int i = 0; i < 4; ++i)
            af[i] = *(const frag16*)(As + (wm + i * 16 + fr) * 32 + quad * 8);
#pragma unroll
        for (int i = 0; i < 2; ++i)
            bfr[i] = *(const frag16*)(Bs + (wn + i * 16 + fr) * 32 + quad * 8);
#pragma unroll
        for (int mi = 0; mi < 4; ++mi)
#pragma unroll
            for (int ni = 0; ni < 2; ++ni)
                acc[mi][ni] = __builtin_amdgcn_mfma_f32_16x16x32_bf16(
                    af[mi], bfr[ni], acc[mi][ni], 0, 0, 0);
        __syncthreads();
    }

    const int fr = lane & 15;
    const int quad = lane >> 4;

    if (trans) {
#pragma unroll
        for (int mi = 0; mi < 4; ++mi)
#pragma unroll
            for (int ni = 0; ni < 2; ++ni) {
                const int m = bm + wm + mi * 16 + quad * 4;
                const int n = bn + wn + ni * 16 + fr;
                ushort4v o;
#pragma unroll
                for (int r = 0; r < 4; ++r) o[r] = f2b(acc[mi][ni][r] + bias[n]);
                const int bb = m >> 9, s = m & 511;
                const int hh = n >> 6, dd = n & 63;
                *(ushort4v*)(CbT + (((size_t)((bb * Hdim + hh) * DKdim + dd)) << 9) + s) = o;
            }
        return;
    }

#pragma unroll
    for (int mi = 0; mi < 4; ++mi) {
#pragma unroll
        for (int r = 0; r < 4; ++r) {
            const int m = bm + wm + mi * 16 + quad * 4 + r;
#pragma unroll
            for (int ni = 0; ni < 2; ++ni) {
                const int n = bn + wn + ni * 16 + fr;
                float v = acc[mi][ni][r] + bias[n];
                if (R) v += R[(size_t)m * NN + n];
                if (Cf) Cf[(size_t)m * NN + n] = v;
                if (Cb) Cb[(size_t)m * NN + n] = f2b(v);
            }
        }
    }
}

// ---------------------------------------------------------------------------
// fp32 -> bf16 convert
// ---------------------------------------------------------------------------
__global__ __launch_bounds__(256) void conv_b(
    const float* __restrict__ X, unsigned short* __restrict__ Y)
{
    const size_t i = ((size_t)blockIdx.x * 256 + threadIdx.x) * 8;
    float4 a = *(const float4*)(X + i);
    float4 b = *(const float4*)(X + i + 4);
    ushort8 o;
    o[0] = f2b(a.x); o[1] = f2b(a.y); o[2] = f2b(a.z); o[3] = f2b(a.w);
    o[4] = f2b(b.x); o[5] = f2b(b.y); o[6] = f2b(b.z); o[7] = f2b(b.w);
    *(ushort8*)(Y + i) = o;
}

// ---------------------------------------------------------------------------
// ALL weight transposes fused: 1600 tiles of 64x64, [K,N] fp32 -> [N,K] bf16
// ---------------------------------------------------------------------------
__global__ __launch_bounds__(256) void wtrans_all(
    const float* __restrict__ Wk, const float* __restrict__ Wv,
    const float* __restrict__ Wo, const float* __restrict__ W1,
    const float* __restrict__ W2, unsigned short* __restrict__ dst)
{
    const int bid = blockIdx.x;
    const float* src; unsigned short* d; int K, N, tk, tn;
    if (bid < 576) {
        const int mat = bid >> 6, tile = bid & 63;
        const int l = mat / 3, wch = mat % 3;
        const float* W = (wch == 0) ? Wk : (wch == 1) ? Wv : Wo;
        src = W + (size_t)l * 262144;
        d = dst + (size_t)mat * 262144;
        K = 512; N = 512; tn = tile & 7; tk = tile >> 3;
    } else if (bid < 1088) {
        const int idx = bid - 576, l2 = idx >> 8, tile = idx & 255;
        src = W1 + (size_t)(l2 * 2) * (512 * 2048);
        d = dst + 9 * 262144 + (size_t)l2 * (512 * 2048);
        K = 512; N = 2048; tn = tile & 31; tk = tile >> 5;
    } else {
        const int idx = bid - 1088, l2 = idx >> 8, tile = idx & 255;
        src = W2 + (size_t)(l2 * 2) * (2048 * 512);
        d = dst + 9 * 262144 + 2 * (512 * 2048) + (size_t)l2 * (2048 * 512);
        K = 2048; N = 512; tn = tile & 7; tk = tile >> 3;
    }
    const int n0 = tn * 64, k0 = tk * 64;
    __shared__ float T[64][65];
    const int t = threadIdx.x;
    const int kl = t >> 4, n4 = (t & 15) << 2;
#pragma unroll
    for (int it = 0; it < 4; ++it) {
        const int k = kl + it * 16;
        float4 v = *(const float4*)(src + (size_t)(k0 + k) * N + n0 + n4);
        T[n4 + 0][k] = v.x; T[n4 + 1][k] = v.y;
        T[n4 + 2][k] = v.z; T[n4 + 3][k] = v.w;
    }
    __syncthreads();
    const int nl = t >> 3, k8 = (t & 7) << 3;
#pragma unroll
    for (int it = 0; it < 2; ++it) {
        const int n = nl + it * 32;
        ushort8 o;
#pragma unroll
        for (int c = 0; c < 8; ++c) o[c] = f2b(T[n][k8 + c]);
        *(ushort8*)(d + (size_t)(n0 + n) * K + k0 + k8) = o;
    }
}

// ---------------------------------------------------------------------------
// Flash-style monotonic attention v2. One wave = 16 q-rows, no inter-wave
// sync. MFMA operands swapped (C[m=j][n=q]): each lane owns ONE q-row (fr)
// and 4 consecutive j -> suffix scan = 3 reg adds + 2 shfl (quad scan).
// Pass 1: sum1 + per-tile totals -> LDS CT; 16-lane serial pass converts to
// strict cross-tile suffix. Pass 2 tiles fully independent (no serial chain).
// Fully-masked row (mask0, i==0): uniform 1/512 over ALL j.
// ---------------------------------------------------------------------------
__global__ __launch_bounds__(256, 4) void attn_flash2(
    const unsigned short* __restrict__ Kb,   // [B*S, D] bf16 (Q == K)
    const unsigned short* __restrict__ Vt,   // [B,H,DK,S] bf16
    const float* __restrict__ gam,
    unsigned short* __restrict__ Ob,         // [B*S, D] bf16
    int mask_type)
{
    __shared__ float CTs[4][16 * 33];            // cross-tile strict suffix
    __shared__ unsigned short Pst[4][16 * 36];   // P staging (A-frag layout)

    const int h = blockIdx.y, b = blockIdx.z;
    const int qt = (blockIdx.x + blockIdx.y + blockIdx.z) & 7;   // balance swizzle
    const int t = threadIdx.x, lane = t & 63, w = t >> 6;
    const int quad = lane >> 4, fr = lane & 15;
    const int q0 = qt * 64 + w * 16;
    const int iRow = q0 + fr;                // this lane's q row

    const unsigned short* kbase = Kb + (size_t)b * Sdim * Ddim + h * DKdim;

    // Q as B-operand: rows q0+fr
    frag16 aq0 = *(const frag16*)(kbase + (size_t)(q0 + fr) * Ddim + quad * 8);
    frag16 aq1 = *(const frag16*)(kbase + (size_t)(q0 + fr) * Ddim + 32 + quad * 8);

    float* CTw = CTs[w];
    const int jnmax = (q0 + 15) >> 4;

    // ---- Pass 1: sum1 partials + per-tile totals into CT
    float psum = 0.f;
    for (int jn = 0; jn <= jnmax; ++jn) {
        frag16 k0 = *(const frag16*)(kbase + (size_t)(jn * 16 + fr) * Ddim + quad * 8);
        frag16 k1 = *(const frag16*)(kbase + (size_t)(jn * 16 + fr) * Ddim + 32 + quad * 8);
        f32x4 z = {0.f, 0.f, 0.f, 0.f};
        z = __builtin_amdgcn_mfma_f32_16x16x32_bf16(k0, aq0, z, 0, 0, 0);
        z = __builtin_amdgcn_mfma_f32_16x16x32_bf16(k1, aq1, z, 0, 0, 0);
        const int jbase = jn * 16 + quad * 4;
        float tq = 0.f;
#pragma unroll
        for (int r = 0; r < 4; ++r) {
            const int j = jbase + r;
            const bool valid = mask_type ? (j <= iRow) : (j < iRow);
            tq += valid ? __expf(z[r] * 0.125f) : 0.f;
        }
        psum += tq;
        float tt = tq;
        tt += __shfl_xor(tt, 16);
        tt += __shfl_xor(tt, 32);
        if (quad == 0) CTw[fr * 33 + jn] = tt;
    }
    float sum1 = psum;
    sum1 += __shfl_xor(sum1, 16);
    sum1 += __shfl_xor(sum1, 32);
    const float rsum1 = 1.f / sum1;          // inf iff fully masked row

    // totals -> strict suffix (rows by lanes 0..15; wave-synchronous)
    if (lane < 16) {
        float run = 0.f;
        for (int jn = 31; jn >= 0; --jn) {
            const float tv = (jn <= jnmax) ? CTw[lane * 33 + jn] : 0.f;
            CTw[lane * 33 + jn] = run;
            run += tv;
        }
    }

    const float gneg = -log1pf(__expf(gam[h]));   // -softplus(gamma)

    // ---- Pass 2: independent tiles, online PV
    unsigned short* Pw = Pst[w];
    const unsigned short* vtb = Vt + (size_t)(b * Hdim + h) * DKdim * Sdim;
    const bool fm_wave = (mask_type == 0) && (q0 == 0);
    const bool fmrow = (mask_type == 0) && (iRow == 0);
    const int umax = fm_wave ? (Sdim / 32 - 1) : ((q0 + 15) >> 5);
    float sum2p = 0.f;
    f32x4 oacc[4] = {};

    for (int u = umax; u >= 0; --u) {
#pragma unroll
        for (int half = 0; half < 2; ++half) {
            const int jn = 2 * u + half;
            frag16 k0 = *(const frag16*)(kbase + (size_t)(jn * 16 + fr) * Ddim + quad * 8);
            frag16 k1 = *(const frag16*)(kbase + (size_t)(jn * 16 + fr) * Ddim + 32 + quad * 8);
            f32x4 z = {0.f, 0.f, 0.f, 0.f};
            z = __builtin_amdgcn_mfma_f32_16x16x32_bf16(k0, aq0, z, 0, 0, 0);
            z = __builtin_amdgcn_mfma_f32_16x16x32_bf16(k1, aq1, z, 0, 0, 0);
            const int jbase = jn * 16 + quad * 4;
            float s[4], e1[4], lsuf[4];
            float tq = 0.f;
#pragma unroll
            for (int r = 3; r >= 0; --r) {
                lsuf[r] = tq;                      // strict suffix within 4-run
                const int j = jbase + r;
                const bool valid = mask_type ? (j <= iRow) : (j < iRow);
                s[r] = z[r] * 0.125f;
                e1[r] = valid ? __expf(s[r]) : 0.f;
                tq += e1[r];
            }
            // strict suffix over quads (2 guarded shfl_down)
            float incl = tq;
            {
                float u1 = __shfl_down(incl, 16);
                incl += (quad < 3) ? u1 : 0.f;
                float u2 = __shfl_down(incl, 32);
                incl += (quad < 2) ? u2 : 0.f;
            }
            const float qsuf = incl - tq;
            const float ct = CTw[fr * 33 + jn];
            ushort4v pk;
#pragma unroll
            for (int r = 0; r < 4; ++r) {
                const int j = jbase + r;
                const bool valid = mask_type ? (j <= iRow) : (j < iRow);
                const float suf = ct + qsuf + lsuf[r];
                const float ratio = suf * rsum1;
                const int dd = iRow - j;
                const float pos = (float)(dd >= 0 ? dd : -dd);
                const float arg = (ratio > 0.f) ? ratio * pos : 0.f;   // NaN-safe
                const float te = fminf(fmaxf(__expf(gneg * sqrtf(arg)), 1e-5f), 1e5f);
                const float e2 = valid ? __expf(s[r] * te) : (fmrow ? 1.f : 0.f);
                sum2p += e2;
                pk[r] = f2b(e2);
            }
            *(ushort4v*)(Pw + fr * 36 + half * 16 + quad * 4) = pk;
        }
        // PV over this pair's 32-wide window (A = P from LDS, B = Vt)
        frag16 pf = *(const frag16*)(Pw + fr * 36 + quad * 8);
        const int jb = u * 32;
#pragma unroll
        for (int dt = 0; dt < 4; ++dt) {
            frag16 vf = *(const frag16*)(vtb + (size_t)(dt * 16 + fr) * Sdim + jb + quad * 8);
            oacc[dt] = __builtin_amdgcn_mfma_f32_16x16x32_bf16(pf, vf, oacc[dt], 0, 0, 0);
        }
    }

    float sum2 = sum2p;
    sum2 += __shfl_xor(sum2, 16);
    sum2 += __shfl_xor(sum2, 32);
    const float rs2 = 1.f / sum2;            // for row fr
    float rs2q[4];
#pragma unroll
    for (int r = 0; r < 4; ++r) rs2q[r] = __shfl(rs2, quad * 4 + r);

    // O rows q0+quad*4+r, cols dt*16+fr
    unsigned short* obase = Ob + ((size_t)(b * Sdim + q0)) * Ddim + h * DKdim;
#pragma unroll
    for (int dt = 0; dt < 4; ++dt)
#pragma unroll
        for (int r = 0; r < 4; ++r)
            obase[(size_t)(quad * 4 + r) * Ddim + dt * 16 + fr] = f2b(oacc[dt][r] * rs2q[r]);
}

// ---------------------------------------------------------------------------
// LayerNorm over last dim (512); fp32 out (nullable) + bf16 out (nullable).
// ---------------------------------------------------------------------------
__global__ __launch_bounds__(256) void ln_kernel(
    const float* __restrict__ X, const float* __restrict__ g,
    const float* __restrict__ bta, float* __restrict__ Y,
    unsigned short* __restrict__ Yb)
{
    const int row = blockIdx.x;
    const int t = threadIdx.x;
    __shared__ float r1[256], r2[256];
    const float* x = X + (size_t)row * Ddim;
    float a = x[t], b = x[t + 256];
    r1[t] = a + b;
    r2[t] = a * a + b * b;
    __syncthreads();
    for (int off = 128; off; off >>= 1) {
        if (t < off) { r1[t] += r1[t + off]; r2[t] += r2[t + off]; }
        __syncthreads();
    }
    float mean = r1[0] * (1.f / Ddim);
    float var = r2[0] * (1.f / Ddim) - mean * mean;
    float rs = rsqrtf(var + 1e-5f);
    float y0 = (a - mean) * rs * g[t] + bta[t];
    float y1 = (b - mean) * rs * g[t + 256] + bta[t + 256];
    if (Y) {
        float* y = Y + (size_t)row * Ddim;
        y[t] = y0;
        y[t + 256] = y1;
    }
    if (Yb) {
        unsigned short* yb = Yb + (size_t)row * Ddim;
        yb[t] = f2b(y0);
        yb[t + 256] = f2b(y1);
    }
}

// ---------------------------------------------------------------------------
extern "C" void kernel_launch(void* const* d_in, const int* in_sizes, int n_in,
                              void* d_out, int out_size, void* d_ws, size_t ws_size,
                              hipStream_t stream)
{
    const float* x0     = (const float*)d_in[0];
    const float* y0     = (const float*)d_in[1];
    const float* Wk     = (const float*)d_in[2];
    const float* bk     = (const float*)d_in[3];
    const float* Wv     = (const float*)d_in[4];
    const float* bv     = (const float*)d_in[5];
    const float* Wo     = (const float*)d_in[6];
    const float* bo     = (const float*)d_in[7];
    const float* gammas = (const float*)d_in[8];
    const float* ln1g   = (const float*)d_in[9];
    const float* ln1b   = (const float*)d_in[10];
    const float* W1     = (const float*)d_in[11];
    const float* b1     = (const float*)d_in[12];
    const float* W2     = (const float*)d_in[13];
    const float* b2     = (const float*)d_in[14];
    const float* ln2g   = (const float*)d_in[15];
    const float* ln2b   = (const float*)d_in[16];

    const size_t NBSD = (size_t)Mrows * Ddim;   // 4,194,304
    float* ws = (float*)d_ws;
    float* T1   = ws;
    float* X1   = T1 + NBSD;
    float* Xbuf = X1 + NBSD;
    unsigned short* Kbf = (unsigned short*)(Xbuf + NBSD);
    unsigned short* Vt  = Kbf + NBSD;
    unsigned short* AOb = Vt + NBSD;
    unsigned short* Abf = AOb + NBSD;
    unsigned short* Xbf = Abf + NBSD;
    unsigned short* Ybf = Xbf + NBSD;
    unsigned short* Hbb = Ybf + NBSD;                       // [M,F]
    unsigned short* WtAll = Hbb + (size_t)Mrows * Fdim;

    auto WtK = [&](int l) { return WtAll + (size_t)(l * 3 + 0) * 262144; };
    auto WtV = [&](int l) { return WtAll + (size_t)(l * 3 + 1) * 262144; };
    auto WtO = [&](int l) { return WtAll + (size_t)(l * 3 + 2) * 262144; };
    auto Wt1 = [&](int l) { return WtAll + 9 * 262144 + (size_t)(l >> 1) * (512 * 2048); };
    auto Wt2 = [&](int l) { return WtAll + 9 * 262144 + 2 * (512 * 2048) + (size_t)(l >> 1) * (2048 * 512); };

    const int convBlocks = (int)(NBSD / 2048);

    wtrans_all<<<1600, 256, 0, stream>>>(Wk, Wv, Wo, W1, W2, WtAll);

    auto run_block = [&](int l, const float* qinf, const unsigned short* qinb,
                         const unsigned short* vinb, int mask_type, bool ffn,
                         float* outf, unsigned short* outb) {
        const float* bk_l = bk + (size_t)l * Ddim;
        const float* bv_l = bv + (size_t)l * Ddim;
        const float* bo_l = bo + (size_t)l * Ddim;

        // K (=Q) + V projections in one launch (z=0: K->Kbf, z=1: V->Vt)
        gemm_n64<<<dim3(8, 64, 2), 256, 0, stream>>>(
            qinb, vinb, WtK(l), WtV(l), bk_l, bv_l,
            nullptr, nullptr, Kbf, Vt, Ddim);
        // attention (flash-style streaming, independent tiles)
        attn_flash2<<<dim3(Sdim / 64, Hdim, Bdim), 256, 0, stream>>>(
            Kbf, Vt, gammas + (size_t)l * Hdim, AOb, mask_type);
        // O-projection + residual -> T1 (fp32); LN1
        gemm_n64<<<dim3(8, 64, 1), 256, 0, stream>>>(
            AOb, AOb, WtO(l), WtO(l), bo_l, bo_l,
            qinf, T1, nullptr, nullptr, Ddim);
        float* x1f = ffn ? X1 : outf;
        unsigned short* x1b = ffn ? Abf : outb;
        ln_kernel<<<Mrows, 256, 0, stream>>>(T1,
            ln1g + (size_t)l * Ddim, ln1b + (size_t)l * Ddim, x1f, x1b);
        if (ffn) {
            const float* b1_l = b1 + (size_t)l * Fdim;
            const float* b2_l = b2 + (size_t)l * Ddim;
            gemm_mfma<<<dim3(Fdim / 128, Mrows / 128), 256, 0, stream>>>(
                (const __hip_bfloat16*)Abf, (const __hip_bfloat16*)Wt1(l),
                b1_l, nullptr, nullptr, Hbb, Mrows, Fdim, Ddim, 1);
            gemm_n64<<<dim3(8, 64, 1), 256, 0, stream>>>(
                Hbb, Hbb, Wt2(l), Wt2(l), b2_l, b2_l,
                X1, T1, nullptr, nullptr, Fdim);
            ln_kernel<<<Mrows, 256, 0, stream>>>(T1,
                ln2g + (size_t)l * Ddim, ln2b + (size_t)l * Ddim, outf, outb);
        }
    };

    // Block 0: knowledge encoder (y), mask1, FFN -> Ybf (bf16 only)
    conv_b<<<convBlocks, 256, 0, stream>>>(y0, Abf);
    run_block(0, y0, Abf, Abf, 1, true, nullptr, Ybf);
    // Block 1: question encoder (x), mask1, no FFN -> Xbuf/Xbf
    conv_b<<<convBlocks, 256, 0, stream>>>(x0, Abf);
    run_block(1, x0, Abf, Abf, 1, false, Xbuf, Xbf);
    // Block 2: knowledge retriever, q/k=x, v=y, mask0, FFN -> d_out (fp32)
    run_block(2, Xbuf, Xbf, Ybf, 0, true, (float*)d_out, nullptr);
}